// Round 6
// baseline (201.088 us; speedup 1.0000x reference)
//
#include <hip/hip_runtime.h>
#include <stdint.h>

// ts_corr: X (16384, 15, 100) f32 -> corr (16384, 105, 10) f32
// corr[b,p(i,j),w] = (dot_ij/10 - mu_i*mu_j) * isd_i * isd_j   (raw-moment form)
//
// R5/R6 redesign: R2/R4 showed the kernel is L1-transaction-bound (40B-stride
// lane patterns -> ~40 lines per wave instruction) plus register spills.
// Stage input AND output tiles in LDS so all global traffic is coalesced
// dwordx4; group-tiled pair compute (5+5 series live) keeps the register
// live set ~110 floats (no spills); double-buffered input with async
// global_load_lds prefetch overlaps copy with compute.
// R6: fix compile error (macro-before-def) -- dots_tri uses A directly.

#define NSER   15
#define TLEN   100
#define DWIN   10
#define WCNT   10
#define NPAIR  105
#define TB     8                       // batches per tile
#define NTHR   128
#define NBLK   256
#define TPB    8                       // tiles per block: 16384/(8*256)
#define IN_F   (TB * NSER * TLEN)      // 12000 floats = 48000 B per tile
#define OUT_F  (TB * NPAIR * WCNT)     // 8400 floats  = 33600 B per tile
#define LDS_BYTES ((2 * IN_F + OUT_F) * 4)   // 129600

// ---- async global->LDS copy of one input tile (fire-and-forget) ----
__device__ inline void issue_tile_copy(const float* __restrict__ g, float* l, int tid) {
    // 48000 B = 3000 x 16B chunks; 128 threads
    #pragma unroll
    for (int k0 = 0; k0 < 3000; k0 += NTHR) {
        const int k = k0 + tid;
        if (k < 3000) {
            __builtin_amdgcn_global_load_lds(
                (const __attribute__((address_space(1))) uint32_t*)(g + k * 4),
                (__attribute__((address_space(3))) uint32_t*)(l + k * 4),
                16, 0, 0);
        }
    }
}

// ---- load 5 series rows (one group) from LDS into registers ----
template <int G>
__device__ inline void load_group(const float* base, float R[5][DWIN]) {
    #pragma unroll
    for (int r = 0; r < 5; ++r) {
        #pragma unroll
        for (int d = 0; d < DWIN; d += 2) {
            float2 v = *reinterpret_cast<const float2*>(base + (G * 5 + r) * TLEN + d);
            R[r][d] = v.x; R[r][d + 1] = v.y;
        }
    }
}

template <int G>
__device__ inline void stats(const float R[5][DWIN], float* mu, float* isd) {
    #pragma unroll
    for (int r = 0; r < 5; ++r) {
        float s1 = 0.f, s2 = 0.f;
        #pragma unroll
        for (int d = 0; d < DWIN; ++d) { s1 += R[r][d]; s2 += R[r][d] * R[r][d]; }
        const float m = s1 * 0.1f;
        mu[G * 5 + r]  = m;
        isd[G * 5 + r] = rsqrtf((s2 - 10.f * m * m) * (1.f / 9.f));
    }
}

__device__ inline void emit(float* ob, int i, int j, float dot,
                            const float* mu, const float* isd) {
    const int p = i * (29 - i) / 2 + (j - i - 1);   // triu_indices order
    ob[p * WCNT] = (dot * 0.1f - mu[i] * mu[j]) * isd[i] * isd[j];
}

template <int GA, int GB>   // GA < GB: all 25 cross pairs
__device__ inline void dots_rect(const float A[5][DWIN], const float B[5][DWIN],
                                 const float* mu, const float* isd, float* ob) {
    #pragma unroll
    for (int ri = 0; ri < 5; ++ri) {
        #pragma unroll
        for (int rj = 0; rj < 5; ++rj) {
            float dot = 0.f;
            #pragma unroll
            for (int d = 0; d < DWIN; ++d) dot += A[ri][d] * B[rj][d];
            emit(ob, GA * 5 + ri, GB * 5 + rj, dot, mu, isd);
        }
    }
}

template <int G>            // within-group upper triangle (10 pairs)
__device__ inline void dots_tri(const float A[5][DWIN],
                                const float* mu, const float* isd, float* ob) {
    #pragma unroll
    for (int ri = 0; ri < 5; ++ri) {
        #pragma unroll
        for (int rj = ri + 1; rj < 5; ++rj) {
            float dot = 0.f;
            #pragma unroll
            for (int d = 0; d < DWIN; ++d) dot += A[ri][d] * A[rj][d];
            emit(ob, G * 5 + ri, G * 5 + rj, dot, mu, isd);
        }
    }
}

__global__ __launch_bounds__(NTHR, 2) void ts_corr_kernel(const float* __restrict__ X,
                                                          float* __restrict__ out) {
    extern __shared__ float smem[];
    float* in0   = smem;
    float* in1   = smem + IN_F;
    float* out_s = smem + 2 * IN_F;

    const int tid = threadIdx.x;
    const int blk = blockIdx.x;

    // prologue: tile 0 -> buf0
    issue_tile_copy(X + (size_t)(blk * TPB) * IN_F, in0, tid);
    __syncthreads();    // drains vmcnt: tile 0 resident

    for (int t = 0; t < TPB; ++t) {
        float* cur = (t & 1) ? in1 : in0;
        float* nxt = (t & 1) ? in0 : in1;
        const size_t tile = (size_t)(blk * TPB + t);

        if (t + 1 < TPB)
            issue_tile_copy(X + (tile + 1) * IN_F, nxt, tid);   // async prefetch

        if (tid < TB * WCNT) {
            const int b_l = tid / WCNT, w = tid % WCNT;
            const float* base = cur + b_l * (NSER * TLEN) + w * DWIN;
            float* ob = out_s + b_l * (NPAIR * WCNT) + w;
            float A[5][DWIN], B[5][DWIN], mu[NSER], isd[NSER];

            load_group<0>(base, A); stats<0>(A, mu, isd);
            dots_tri<0>(A, mu, isd, ob);
            load_group<1>(base, B); stats<1>(B, mu, isd);
            dots_rect<0, 1>(A, B, mu, isd, ob);
            dots_tri<1>(B, mu, isd, ob);
            load_group<2>(base, A); stats<2>(A, mu, isd);
            dots_rect<1, 2>(B, A, mu, isd, ob);
            dots_tri<2>(A, mu, isd, ob);
            load_group<0>(base, B);                     // reload G0 (stats cached)
            dots_rect<0, 2>(B, A, mu, isd, ob);
        }
        __syncthreads();   // out_s complete; prefetch landed (vmcnt drain)

        // coalesced writeout: 8400 floats = 2100 float4
        float* og = out + tile * OUT_F;
        #pragma unroll
        for (int k0 = 0; k0 < 2100; k0 += NTHR) {
            const int k = k0 + tid;
            if (k < 2100) {
                float4 v = *reinterpret_cast<const float4*>(out_s + k * 4);
                *reinterpret_cast<float4*>(og + k * 4) = v;
            }
        }
        __syncthreads();   // out_s reusable
    }
}

extern "C" void kernel_launch(void* const* d_in, const int* in_sizes, int n_in,
                              void* d_out, int out_size, void* d_ws, size_t ws_size,
                              hipStream_t stream) {
    const float* X = (const float*)d_in[0];
    float* out = (float*)d_out;
    (void)hipFuncSetAttribute((const void*)ts_corr_kernel,
                              hipFuncAttributeMaxDynamicSharedMemorySize, LDS_BYTES);
    ts_corr_kernel<<<NBLK, NTHR, LDS_BYTES, stream>>>(X, out);
}

// Round 9
// 182.251 us; speedup vs baseline: 1.1034x; 1.1034x over previous
//
#include <hip/hip_runtime.h>

// ts_corr: X (16384, 15, 100) f32 -> corr (16384, 105, 10) f32
// corr[b,p(i,j),w] = (dot_ij/10 - mu_i*mu_j) * isd_i * isd_j   (raw-moment form)
//
// R7: register-tiled groups of 3 series, NO LDS (R6: 129KB LDS -> 1 block/CU,
// 5% occupancy, bank conflicts). Live set = two 30-float group buffers +
// mu/isd (30) ~= 95 floats.
// R9: fix operand swap in step 7 (rect<0,2> got A=g2,B=g0 -> absmax 7.6).

#define NSER   15
#define TLEN   100
#define DWIN   10
#define WCNT   10
#define NPAIR  105

// Load 3 series rows (group G) of one (b,w) window from global (L1-cached).
template <int G>
__device__ inline void load3(const float* __restrict__ Xb, float R[3][DWIN]) {
    #pragma unroll
    for (int r = 0; r < 3; ++r) {
        const float2* p2 = reinterpret_cast<const float2*>(Xb + (G * 3 + r) * TLEN);
        #pragma unroll
        for (int k = 0; k < 5; ++k) {
            float2 v = p2[k];
            R[r][2 * k] = v.x; R[r][2 * k + 1] = v.y;
        }
    }
}

template <int G>
__device__ inline void stats3(const float R[3][DWIN], float* mu, float* isd) {
    #pragma unroll
    for (int r = 0; r < 3; ++r) {
        float s1 = 0.f, s2 = 0.f;
        #pragma unroll
        for (int d = 0; d < DWIN; ++d) { s1 += R[r][d]; s2 += R[r][d] * R[r][d]; }
        const float m = s1 * 0.1f;
        mu[G * 3 + r]  = m;
        isd[G * 3 + r] = rsqrtf((s2 - 10.f * m * m) * (1.f / 9.f));
    }
}

__device__ inline void emit(float* __restrict__ ob, int i, int j, float dot,
                            const float* mu, const float* isd) {
    const int p = i * (29 - i) / 2 + (j - i - 1);   // triu_indices(15,k=1) order
    ob[p * WCNT] = (dot * 0.1f - mu[i] * mu[j]) * isd[i] * isd[j];
}

template <int GA, int GB>   // A holds group GA, B holds group GB, GA < GB
__device__ inline void rect(const float A[3][DWIN], const float B[3][DWIN],
                            const float* mu, const float* isd, float* __restrict__ ob) {
    #pragma unroll
    for (int ri = 0; ri < 3; ++ri) {
        #pragma unroll
        for (int rj = 0; rj < 3; ++rj) {
            float dot = 0.f;
            #pragma unroll
            for (int d = 0; d < DWIN; ++d) dot += A[ri][d] * B[rj][d];
            emit(ob, GA * 3 + ri, GB * 3 + rj, dot, mu, isd);
        }
    }
}

template <int G>            // within-group pairs (3)
__device__ inline void tri(const float A[3][DWIN],
                           const float* mu, const float* isd, float* __restrict__ ob) {
    #pragma unroll
    for (int ri = 0; ri < 3; ++ri) {
        #pragma unroll
        for (int rj = ri + 1; rj < 3; ++rj) {
            float dot = 0.f;
            #pragma unroll
            for (int d = 0; d < DWIN; ++d) dot += A[ri][d] * A[rj][d];
            emit(ob, G * 3 + ri, G * 3 + rj, dot, mu, isd);
        }
    }
}

__global__ __launch_bounds__(256) void ts_corr_kernel(const float* __restrict__ X,
                                                      float* __restrict__ out) {
    const int task = blockIdx.x * 256 + threadIdx.x;
    const int b = task / WCNT;
    const int w = task % WCNT;

    const float* Xb = X + (size_t)b * (NSER * TLEN) + w * DWIN;
    float* ob = out + (size_t)b * (NPAIR * WCNT) + w;

    float S[3][DWIN], T[3][DWIN], mu[NSER], isd[NSER];

    // 11-step schedule over 2 register slots covers all 10 rects + 5 tris.
    // Invariant: rect<GA,GB>(A,B) must get A=group GA, B=group GB.
    load3<0>(Xb, S); stats3<0>(S, mu, isd); tri<0>(S, mu, isd, ob);
    load3<1>(Xb, T); stats3<1>(T, mu, isd); rect<0,1>(S, T, mu, isd, ob); tri<1>(T, mu, isd, ob);
    load3<2>(Xb, S); stats3<2>(S, mu, isd); rect<1,2>(T, S, mu, isd, ob); tri<2>(S, mu, isd, ob);
    load3<3>(Xb, T); stats3<3>(T, mu, isd); rect<2,3>(S, T, mu, isd, ob); tri<3>(T, mu, isd, ob);
    load3<4>(Xb, S); stats3<4>(S, mu, isd); rect<3,4>(T, S, mu, isd, ob); tri<4>(S, mu, isd, ob);
    load3<0>(Xb, T); rect<0,4>(T, S, mu, isd, ob);   // T=g0, S=g4
    load3<2>(Xb, S); rect<0,2>(T, S, mu, isd, ob);   // T=g0, S=g2  (R9 fix: was S,T)
    load3<4>(Xb, T); rect<2,4>(S, T, mu, isd, ob);   // S=g2, T=g4
    load3<1>(Xb, S); rect<1,4>(S, T, mu, isd, ob);   // S=g1, T=g4
    load3<3>(Xb, T); rect<1,3>(S, T, mu, isd, ob);   // S=g1, T=g3
    load3<0>(Xb, S); rect<0,3>(S, T, mu, isd, ob);   // S=g0, T=g3
}

extern "C" void kernel_launch(void* const* d_in, const int* in_sizes, int n_in,
                              void* d_out, int out_size, void* d_ws, size_t ws_size,
                              hipStream_t stream) {
    const float* X = (const float*)d_in[0];
    float* out = (float*)d_out;
    const int total = 16384 * WCNT;                 // 163840 tasks
    ts_corr_kernel<<<total / 256, 256, 0, stream>>>(X, out);
}